// Round 6
// baseline (1315.441 us; speedup 1.0000x reference)
//
#include <hip/hip_runtime.h>

typedef unsigned short u16;
typedef __attribute__((ext_vector_type(8))) short short8;
typedef __attribute__((ext_vector_type(4))) float f32x4;

__device__ __forceinline__ u16 f2bf(float f) {
  union { float f; unsigned u; } v; v.f = f;
  unsigned r = v.u + 0x7fffu + ((v.u >> 16) & 1u);
  return (u16)(r >> 16);
}
__device__ __forceinline__ u16 truncbf(float f) {
  union { float f; unsigned u; } v; v.f = f;
  return (u16)(v.u >> 16);
}
__device__ __forceinline__ float bf2f(u16 h) {
  union { unsigned u; float f; } v; v.u = ((unsigned)h) << 16;
  return v.f;
}
// async global->LDS, 16B per lane; LDS dest = wave-uniform base (HW adds lane*16), 16B aligned
__device__ __forceinline__ void gll16(const void* g, void* l) {
  __builtin_amdgcn_global_load_lds((const __attribute__((address_space(1))) unsigned*)g,
                                   (__attribute__((address_space(3))) unsigned*)l, 16, 0, 0);
}

// Problem constants
#define BATCH 512
#define TS 1023          // T-1
#define NF 64
#define NS 128
#define NH 128
#define NG 384           // 3H
#define NC 192           // F + SNN
#define TCH 341          // t-chunk for xproj/gru; M per chunk = 341*512 = 1364*128
// All big tensors are t-major: tensor[t][b][feat], flat row m = t*512 + b.

// ---------------- P: weight bf16 conversion ----------------
__global__ void k_prep(const float* __restrict__ wih, const float* __restrict__ w1,
                       u16* __restrict__ wihb, u16* __restrict__ w1b) {
  int i = blockIdx.x * 256 + threadIdx.x;
  if (i < NG * NC) wihb[i] = f2bf(wih[i]);
  if (i < 64 * NH) w1b[i] = f2bf(w1[i]);
}

// ---------------- FRONT: fused delta-GEMM (bf16 hi/lo MFMA) + SNN scan + raw ----------------
// One block per batch b (512 blocks, 256 threads). Streams t in 16 tiles of 64.
__global__ __launch_bounds__(256) void k_front(const float* __restrict__ x,
                                               const float* __restrict__ pw,
                                               const float* __restrict__ pb,
                                               const float* __restrict__ beta1,
                                               const float* __restrict__ beta2,
                                               u16* __restrict__ hcomb) {
  __shared__ alignas(16) float xs[17 * 256];        // 17,408 B: up to 65 rows x 64 f + pad
  __shared__ alignas(16) u16 Ahi[64 * 64], Alo[64 * 64];   // 8 KB each, XOR-swizzled rows
  __shared__ alignas(16) u16 Bhi[128 * 64], Blo[128 * 64]; // 16 KB each, XOR-swizzled rows
  __shared__ float hst[64 * 138];                   // 35,328 B (pad 138: quad-writes 2-way free)
  const int tid = threadIdx.x, lane = tid & 63, w = tid >> 6;
  const int m16 = lane & 15, quad = lane >> 4;
  const int b = blockIdx.x;
  const float* xb = x + (long)b * 65536;

  // P0: B = pw hi/lo split, row-major [n][64k], chunk-swizzled
  #pragma unroll
  for (int j = 0; j < 4; ++j) {
    int cid = tid * 4 + j;           // 0..1023
    int n = cid >> 3, ch = cid & 7;
    const float* src = pw + n * 64 + ch * 8;
    short8 h8, l8;
    #pragma unroll
    for (int jj = 0; jj < 8; ++jj) {
      float v = src[jj];
      u16 hh = truncbf(v);
      float l = v - bf2f(hh);
      h8[jj] = (short)hh; l8[jj] = (short)f2bf(l);
    }
    int chs = ch ^ (n & 7);
    *(short8*)(Bhi + n * 64 + chs * 8) = h8;
    *(short8*)(Blo + n * 64 + chs * 8) = l8;
  }
  float b1v = 0.f, b2v = 0.f, m1 = 0.f, s1 = 0.f, m2 = 0.f, s2 = 0.f;
  if (tid < 128) {
    b1v = fminf(fmaxf(beta1[tid], 0.f), 0.99f);
    b2v = fminf(fmaxf(beta2[tid], 0.f), 0.99f);
  }
  const int tm = (w >> 1) * 32, nn = (w & 1) * 64;
  float pbv[4];
  #pragma unroll
  for (int ni = 0; ni < 4; ++ni) pbv[ni] = pb[nn + ni * 16 + m16];

  for (int tile = 0; tile < 16; ++tile) {
    const int t0 = tile * 64;
    const int tl = (TS - t0 < 64) ? (TS - t0) : 64;       // 64, last tile 63
    const int rows = (1024 - t0 < 65) ? (1024 - t0) : 65; // 65, last tile 64
    const int bytes = rows * 256;
    // P1: stage x rows t0..t0+rows-1 (contiguous) via async global->LDS
    const int nch = (bytes + 1023) >> 10;
    for (int c = w; c < nch; c += 4) {
      int off = c * 1024 + lane * 16;
      if (off > bytes - 16) off = bytes - 16;
      gll16((const char*)xb + (long)t0 * 256 + off, (char*)xs + c * 1024);
    }
    __syncthreads();
    // P2: A = delta hi/lo (row r holds t = t0+r), swizzled
    {
      int r = tid >> 2, kq = tid & 3;
      const float* x0 = xs + r * 64 + kq * 16;
      short8 h8[2], l8[2];
      #pragma unroll
      for (int cc = 0; cc < 2; ++cc)
        #pragma unroll
        for (int jj = 0; jj < 8; ++jj) {
          float d = x0[64 + cc * 8 + jj] - x0[cc * 8 + jj];
          u16 hh = truncbf(d);
          float l = d - bf2f(hh);
          h8[cc][jj] = (short)hh; l8[cc][jj] = (short)f2bf(l);
        }
      #pragma unroll
      for (int cc = 0; cc < 2; ++cc) {
        int chs = (kq * 2 + cc) ^ (r & 7);
        *(short8*)(Ahi + r * 64 + chs * 8) = h8[cc];
        *(short8*)(Alo + r * 64 + chs * 8) = l8[cc];
      }
    }
    __syncthreads();
    // P3: MFMA 3-pass hi/lo, wave tile 32t x 64n
    f32x4 acc[2][4] = {};
    #pragma unroll
    for (int kc = 0; kc < 2; ++kc) {
      short8 ah[2], al[2], bh[4], bl[4];
      #pragma unroll
      for (int mi = 0; mi < 2; ++mi) {
        int row = tm + mi * 16 + m16;
        int chs = (kc * 4 + quad) ^ (row & 7);
        ah[mi] = *(const short8*)(Ahi + row * 64 + chs * 8);
        al[mi] = *(const short8*)(Alo + row * 64 + chs * 8);
      }
      #pragma unroll
      for (int ni = 0; ni < 4; ++ni) {
        int row = nn + ni * 16 + m16;
        int chs = (kc * 4 + quad) ^ (row & 7);
        bh[ni] = *(const short8*)(Bhi + row * 64 + chs * 8);
        bl[ni] = *(const short8*)(Blo + row * 64 + chs * 8);
      }
      #pragma unroll
      for (int mi = 0; mi < 2; ++mi)
        #pragma unroll
        for (int ni = 0; ni < 4; ++ni) {
          acc[mi][ni] = __builtin_amdgcn_mfma_f32_16x16x32_bf16(ah[mi], bh[ni], acc[mi][ni], 0, 0, 0);
          acc[mi][ni] = __builtin_amdgcn_mfma_f32_16x16x32_bf16(ah[mi], bl[ni], acc[mi][ni], 0, 0, 0);
          acc[mi][ni] = __builtin_amdgcn_mfma_f32_16x16x32_bf16(al[mi], bh[ni], acc[mi][ni], 0, 0, 0);
        }
    }
    // P4: hst[t][n] = acc + proj_b (C/D layout: col=lane&15, row=quad*4+reg)
    #pragma unroll
    for (int mi = 0; mi < 2; ++mi)
      #pragma unroll
      for (int ni = 0; ni < 4; ++ni)
        #pragma unroll
        for (int rr = 0; rr < 4; ++rr)
          hst[(tm + mi * 16 + quad * 4 + rr) * 138 + nn + ni * 16 + m16] = acc[mi][ni][rr] + pbv[ni];
    __syncthreads();
    // P5: SNN scan (threads 0..127) + raw emit (threads 128..255)
    if (tid < 128) {
      const int n = tid;
      u16* dst = hcomb + ((long)t0 * 512 + b) * NC + 64 + n;
      for (int tt = 0; tt < tl; tt += 8) {
        float v[8];
        #pragma unroll
        for (int jj = 0; jj < 8; ++jj) {
          int t = tt + jj; if (t > 63) t = 63;
          v[jj] = hst[t * 138 + n];
        }
        #pragma unroll
        for (int jj = 0; jj < 8; ++jj) {
          int t = tt + jj;
          if (t < tl) {
            m1 = b1v * m1 + v[jj] - s1;
            s1 = (m1 > 1.0f) ? 1.0f : 0.0f;
            m2 = b2v * m2 + s1 - s2;
            s2 = (m2 > 1.0f) ? 1.0f : 0.0f;
            dst[(long)t * (512 * NC)] = f2bf(m2);
          }
        }
      }
    } else {
      const int f = tid & 63, half = (tid >> 6) & 1;
      for (int r = half; r < tl; r += 2)
        hcomb[((long)(t0 + r) * 512 + b) * NC + f] = f2bf(xs[(r + 1) * 64 + f]);
    }
    __syncthreads();
  }
}

// ---------------- C: x_proj chunk = h_comb @ W_ih^T + b_ih (bf16 MFMA) ----------------
// grid (1364, 3), block 256. BM=128 BN=128 BK=32, 6 k-chunks. hc/xp are chunk-base pointers.
__global__ __launch_bounds__(256) void k_xproj(const u16* __restrict__ hc, const u16* __restrict__ wih,
                                               const float* __restrict__ bih, u16* __restrict__ xp) {
  __shared__ alignas(16) u16 As[4096], Bs[4096];   // 8KB each: 128 rows x 32 bf16 (64B rows)
  const int tid = threadIdx.x, lane = tid & 63, w = tid >> 6;
  const int m16 = lane & 15, quad = lane >> 4;
  const long row0 = (long)blockIdx.x * 128;
  const int n0 = blockIdx.y * 128;
  const int wm = (w >> 1) * 64, wn = (w & 1) * 64;
  f32x4 acc[4][4] = {};
  const char* gA = (const char*)hc + (row0 + (lane >> 2)) * (NC * 2) + (lane & 3) * 16;
  const char* gB = (const char*)wih + (long)(n0 + (lane >> 2)) * (NC * 2) + (lane & 3) * 16;
  for (int kc = 0; kc < 6; ++kc) {
    #pragma unroll
    for (int i = 0; i < 2; ++i) {
      int q = i * 4 + w;
      gll16(gA + (long)q * 16 * (NC * 2) + kc * 64, (char*)As + q * 1024);
      gll16(gB + (long)q * 16 * (NC * 2) + kc * 64, (char*)Bs + q * 1024);
    }
    __syncthreads();
    short8 af[4], bfr[4];
    #pragma unroll
    for (int mi = 0; mi < 4; ++mi) af[mi] = *(const short8*)((const char*)As + (wm + mi * 16 + m16) * 64 + quad * 16);
    #pragma unroll
    for (int ni = 0; ni < 4; ++ni) bfr[ni] = *(const short8*)((const char*)Bs + (wn + ni * 16 + m16) * 64 + quad * 16);
    #pragma unroll
    for (int mi = 0; mi < 4; ++mi)
      #pragma unroll
      for (int ni = 0; ni < 4; ++ni)
        acc[mi][ni] = __builtin_amdgcn_mfma_f32_16x16x32_bf16(af[mi], bfr[ni], acc[mi][ni], 0, 0, 0);
    __syncthreads();
  }
  #pragma unroll
  for (int ni = 0; ni < 4; ++ni) {
    int n = n0 + wn + ni * 16 + m16;
    float bias = bih[n];
    #pragma unroll
    for (int mi = 0; mi < 4; ++mi) {
      long r = row0 + wm + mi * 16 + quad * 4;
      #pragma unroll
      for (int rr = 0; rr < 4; ++rr)
        xp[(r + rr) * NG + n] = f2bf(acc[mi][ni][rr] + bias);
    }
  }
}

// ---------------- D: GRU scan chunk — 1 batch/block, 512 blocks (2/CU), batched global traffic ----------------
// Batch replicated into A rows {0,4,8,12}: every quad's acc reg 0 = gh[b][col] -> gates via cndmask,
// no LDS scratch. Wave w owns gate rows {r,z,n} x j in [32w,32w+32); lane (quad,m16):
// hq=quad>>1, j=32w+hq*16+m16 (quad pairs duplicate; quad&1==0 lanes write).
// xp loads prefetched 8 steps at group boundaries; gout stores buffered 8 steps -> 7 of 8 barriers
// have no vmem to drain (avoids per-step s_waitcnt vmcnt(0) tax).
__global__ __launch_bounds__(256, 2) void k_gru(const u16* __restrict__ xp, const float* __restrict__ whh,
                                                const float* __restrict__ bhh, u16* __restrict__ gout,
                                                float* __restrict__ h_state, int first) {
  __shared__ alignas(16) u16 frag[2 * 2048];   // two 4KB A-fragment ping-pong buffers
  const int tid = threadIdx.x, lane = tid & 63, w = tid >> 6;
  const int m16 = lane & 15, quad = lane >> 4;
  const long bg = blockIdx.x;
  // W_hh fragments: tile nt = g*2+hh -> rows g*128 + 32w + hh*16 + m16, k = c*32 + quad*8 + i
  short8 wf[6][4];
  #pragma unroll
  for (int g = 0; g < 3; ++g)
    #pragma unroll
    for (int hh = 0; hh < 2; ++hh)
      #pragma unroll
      for (int c = 0; c < 4; ++c) {
        const float* src = whh + (long)(g * 128 + 32 * w + hh * 16 + m16) * NH + c * 32 + quad * 8;
        short8 v;
        #pragma unroll
        for (int jj = 0; jj < 8; ++jj) v[jj] = (short)f2bf(src[jj]);
        wf[g * 2 + hh][c] = v;
      }
  const int hq = quad >> 1;
  const int j = 32 * w + hq * 16 + m16;        // this lane's j (quad pairs duplicate)
  const bool wr = (quad & 1) == 0;             // one lane of each duplicate pair does writes
  const float br_ = bhh[j], bz_ = bhh[128 + j], bn_ = bhh[256 + j];
  float h = first ? 0.f : h_state[bg * NH + j];
  // frag byte base for this j; batch copies at A rows {0,4,8,12} -> +0,+64,+128,+192
  const int fragoff = w * 1024 + (hq * 2 + (m16 >> 3)) * 256 + (m16 & 7) * 2;
  if (wr) {
    u16 hb0 = f2bf(h);
    *(u16*)((char*)frag + fragoff + 0) = hb0;
    *(u16*)((char*)frag + fragoff + 64) = hb0;
    *(u16*)((char*)frag + fragoff + 128) = hb0;
    *(u16*)((char*)frag + fragoff + 192) = hb0;
  }
  const u16* xbase = xp + bg * NG + j;         // + t*512*NG; gates at +0,+128,+256
  u16 pr[8], pz[8], pn[8], sbuf[8];
  #pragma unroll
  for (int u = 0; u < 8; ++u) {
    const u16* xr = xbase + (long)u * (512 * NG);
    pr[u] = xr[0]; pz[u] = xr[128]; pn[u] = xr[256];
  }
  __syncthreads();

#define GRU_STEP(T, U)                                                                     \
  {                                                                                        \
    const int cur = ((T) & 1) * 4096, nxt = 4096 - cur;                                    \
    short8 af[4];                                                                          \
    _Pragma("unroll")                                                                      \
    for (int c = 0; c < 4; ++c)                                                            \
      af[c] = *(const short8*)((const char*)frag + cur + c * 1024 + lane * 16);            \
    f32x4 zero = {0.f, 0.f, 0.f, 0.f};                                                     \
    f32x4 acc[6];                                                                          \
    _Pragma("unroll")                                                                      \
    for (int nt = 0; nt < 6; ++nt)                                                         \
      acc[nt] = __builtin_amdgcn_mfma_f32_16x16x32_bf16(af[0], wf[nt][0], zero, 0, 0, 0);  \
    _Pragma("unroll")                                                                      \
    for (int c = 1; c < 4; ++c)                                                            \
      _Pragma("unroll")                                                                    \
      for (int nt = 0; nt < 6; ++nt)                                                       \
        acc[nt] = __builtin_amdgcn_mfma_f32_16x16x32_bf16(af[c], wf[nt][c], acc[nt], 0, 0, 0); \
    float ghr = (hq ? acc[1][0] : acc[0][0]) + br_;                                        \
    float ghz = (hq ? acc[3][0] : acc[2][0]) + bz_;                                        \
    float ghn = (hq ? acc[5][0] : acc[4][0]) + bn_;                                        \
    float xrv = bf2f(pr[U]), xzv = bf2f(pz[U]), xnv = bf2f(pn[U]);                         \
    float rg = 1.f / (1.f + __expf(-(xrv + ghr)));                                         \
    float zg = 1.f / (1.f + __expf(-(xzv + ghz)));                                         \
    float niv = xnv + rg * ghn;                                                            \
    float ng = 1.f - 2.f / (1.f + __expf(2.f * niv));                                      \
    h = (1.f - zg) * ng + zg * h;                                                          \
    u16 hb = f2bf(h);                                                                      \
    sbuf[U] = hb;                                                                          \
    if (wr) {                                                                              \
      *(u16*)((char*)frag + nxt + fragoff + 0) = hb;                                       \
      *(u16*)((char*)frag + nxt + fragoff + 64) = hb;                                      \
      *(u16*)((char*)frag + nxt + fragoff + 128) = hb;                                     \
      *(u16*)((char*)frag + nxt + fragoff + 192) = hb;                                     \
    }                                                                                      \
    __syncthreads();                                                                       \
  }

  for (int t8 = 0; t8 < 336; t8 += 8) {
    // flush previous group's stores (none on first group)
    if (t8 > 0 && wr) {
      #pragma unroll
      for (int u = 0; u < 8; ++u)
        gout[((long)(t8 - 8 + u) * 512 + bg) * NH + j] = sbuf[u];
    }
    // prefetch next group's xp (t8+8 .. t8+15, clamped)
    u16 npr[8], npz[8], npn[8];
    #pragma unroll
    for (int u = 0; u < 8; ++u) {
      long tp = t8 + 8 + u; if (tp > TCH - 1) tp = TCH - 1;
      const u16* xr = xbase + tp * (512 * NG);
      npr[u] = xr[0]; npz[u] = xr[128]; npn[u] = xr[256];
    }
    GRU_STEP(t8 + 0, 0) GRU_STEP(t8 + 1, 1) GRU_STEP(t8 + 2, 2) GRU_STEP(t8 + 3, 3)
    GRU_STEP(t8 + 4, 4) GRU_STEP(t8 + 5, 5) GRU_STEP(t8 + 6, 6) GRU_STEP(t8 + 7, 7)
    #pragma unroll
    for (int u = 0; u < 8; ++u) { pr[u] = npr[u]; pz[u] = npz[u]; pn[u] = npn[u]; }
  }
  // flush group t=328..335
  if (wr) {
    #pragma unroll
    for (int u = 0; u < 8; ++u)
      gout[((long)(328 + u) * 512 + bg) * NH + j] = sbuf[u];
  }
  // tail t = 336..340 (pre holds them), store immediately
  #pragma unroll
  for (int u = 0; u < 5; ++u) {
    GRU_STEP(336 + u, u)
    if (wr) gout[((long)(336 + u) * 512 + bg) * NH + j] = sbuf[u];
  }
#undef GRU_STEP
  if (wr) h_state[bg * NH + j] = h;
}

// ---------------- E: scores = relu(gru@W1^T + b1)@w2 + b2 (bf16 MFMA, fused 2nd layer) ----------------
// grid 4092, block 256. BM=128, BN=64, K=128 (4 chunks). M-rows = t*512+b (t-major).
__global__ __launch_bounds__(256) void k_score(const u16* __restrict__ gbf, const u16* __restrict__ w1,
                                               const float* __restrict__ b1, const float* __restrict__ w2,
                                               const float* __restrict__ b2, float* __restrict__ scores) {
  __shared__ alignas(16) u16 Gs[4096], Ws[2048];
  const int tid = threadIdx.x, lane = tid & 63, w = tid >> 6;
  const int m16 = lane & 15, quad = lane >> 4;
  const long row0 = (long)blockIdx.x * 128;
  f32x4 acc[2][4] = {};
  const char* gG = (const char*)gbf + (row0 + (lane >> 2)) * (NH * 2) + (lane & 3) * 16;
  const char* gW = (const char*)w1 + (long)(w * 16 + (lane >> 2)) * (NH * 2) + (lane & 3) * 16;
  for (int kc = 0; kc < 4; ++kc) {
    #pragma unroll
    for (int i = 0; i < 2; ++i) {
      int q = i * 4 + w;
      gll16(gG + (long)q * 16 * (NH * 2) + kc * 64, (char*)Gs + q * 1024);
    }
    gll16(gW + kc * 64, (char*)Ws + w * 1024);
    __syncthreads();
    short8 af[2], bfr[4];
    #pragma unroll
    for (int mi = 0; mi < 2; ++mi) af[mi] = *(const short8*)((const char*)Gs + (w * 32 + mi * 16 + m16) * 64 + quad * 16);
    #pragma unroll
    for (int ni = 0; ni < 4; ++ni) bfr[ni] = *(const short8*)((const char*)Ws + (ni * 16 + m16) * 64 + quad * 16);
    #pragma unroll
    for (int mi = 0; mi < 2; ++mi)
      #pragma unroll
      for (int ni = 0; ni < 4; ++ni)
        acc[mi][ni] = __builtin_amdgcn_mfma_f32_16x16x32_bf16(af[mi], bfr[ni], acc[mi][ni], 0, 0, 0);
    __syncthreads();
  }
  float b2v = b2[0];
  float w2v[4], b1v[4];
  #pragma unroll
  for (int ni = 0; ni < 4; ++ni) { w2v[ni] = w2[ni * 16 + m16]; b1v[ni] = b1[ni * 16 + m16]; }
  #pragma unroll
  for (int mi = 0; mi < 2; ++mi) {
    #pragma unroll
    for (int rr = 0; rr < 4; ++rr) {
      float v = 0.f;
      #pragma unroll
      for (int ni = 0; ni < 4; ++ni) {
        float hv = acc[mi][ni][rr] + b1v[ni];
        hv = hv > 0.f ? hv : 0.f;
        v = fmaf(hv, w2v[ni], v);
      }
      v += __shfl_xor(v, 1, 64); v += __shfl_xor(v, 2, 64);
      v += __shfl_xor(v, 4, 64); v += __shfl_xor(v, 8, 64);
      if (m16 == 0) scores[row0 + w * 32 + mi * 16 + quad * 4 + rr] = v + b2v;
    }
  }
}

// ---------------- F: softmax over t + weighted sum + head ----------------
// 512 blocks (one per batch) x 256 threads. scores/gout are t-major.
__global__ __launch_bounds__(256) void k_attn(const float* __restrict__ scores, const u16* __restrict__ gout,
                                              const float* __restrict__ headw, const float* __restrict__ headb,
                                              float* __restrict__ out) {
  __shared__ float sc[TS];
  __shared__ float red[8];
  __shared__ float part[8][132];
  __shared__ float hann[128];
  const int tid = threadIdx.x, lane = tid & 63, w = tid >> 6;
  const long b = blockIdx.x;
  const float* srow = scores + b;        // stride 512 per t
  float s0[4];
  #pragma unroll
  for (int i = 0; i < 4; ++i) {
    int t = tid + i * 256;
    s0[i] = (t < TS) ? srow[(long)t * 512] : -1e30f;
  }
  float mx = fmaxf(fmaxf(s0[0], s0[1]), fmaxf(s0[2], s0[3]));
  #pragma unroll
  for (int off = 32; off > 0; off >>= 1) mx = fmaxf(mx, __shfl_xor(mx, off, 64));
  if (lane == 0) red[w] = mx;
  __syncthreads();
  mx = fmaxf(fmaxf(red[0], red[1]), fmaxf(red[2], red[3]));
  float sum = 0.f;
  #pragma unroll
  for (int i = 0; i < 4; ++i) {
    int t = tid + i * 256;
    if (t < TS) { float e = __expf(s0[i] - mx); sc[t] = e; sum += e; }
  }
  #pragma unroll
  for (int off = 32; off > 0; off >>= 1) sum += __shfl_xor(sum, off, 64);
  if (lane == 0) red[4 + w] = sum;
  __syncthreads();
  float inv = 1.f / (red[4] + red[5] + red[6] + red[7]);
  const int jg = tid & 31, sl = tid >> 5;
  float acc[4] = {0.f, 0.f, 0.f, 0.f};
  const u16* gbase = gout + b * NH + jg * 4;   // stride 512*NH per t
  for (int t = sl; t < TS; t += 8) {
    float wt = sc[t];
    ushort4 g4 = *(const ushort4*)(gbase + (long)t * (512 * NH));
    acc[0] = fmaf(wt, bf2f(g4.x), acc[0]);
    acc[1] = fmaf(wt, bf2f(g4.y), acc[1]);
    acc[2] = fmaf(wt, bf2f(g4.z), acc[2]);
    acc[3] = fmaf(wt, bf2f(g4.w), acc[3]);
  }
  #pragma unroll
  for (int i = 0; i < 4; ++i) part[sl][jg * 4 + i] = acc[i];
  __syncthreads();
  if (tid < 128) {
    float v = 0.f;
    #pragma unroll
    for (int s = 0; s < 8; ++s) v += part[s][tid];
    hann[tid] = v * inv;
  }
  __syncthreads();
  if (tid < 24) {
    float a = headb[tid];
    const float* hwr = headw + tid * 128;
    for (int k = 0; k < 128; k += 4) {
      float4 h4 = *(const float4*)&hann[k];
      float4 w4 = *(const float4*)&hwr[k];
      a = fmaf(h4.x, w4.x, a); a = fmaf(h4.y, w4.y, a);
      a = fmaf(h4.z, w4.z, a); a = fmaf(h4.w, w4.w, a);
    }
    out[b * 24 + tid] = a;
  }
}

extern "C" void kernel_launch(void* const* d_in, const int* in_sizes, int n_in,
                              void* d_out, int out_size, void* d_ws, size_t ws_size,
                              hipStream_t stream) {
  const float* x      = (const float*)d_in[0];
  const float* proj_w = (const float*)d_in[1];
  const float* proj_b = (const float*)d_in[2];
  const float* beta1  = (const float*)d_in[3];
  const float* beta2  = (const float*)d_in[4];
  const float* gwih   = (const float*)d_in[5];
  const float* gwhh   = (const float*)d_in[6];
  const float* gbih   = (const float*)d_in[7];
  const float* gbhh   = (const float*)d_in[8];
  const float* aw1    = (const float*)d_in[9];
  const float* ab1    = (const float*)d_in[10];
  const float* aw2    = (const float*)d_in[11];
  const float* ab2    = (const float*)d_in[12];
  const float* hw     = (const float*)d_in[13];
  const float* hb     = (const float*)d_in[14];
  float* out = (float*)d_out;
  char* ws = (char*)d_ws;

  // Workspace (bytes) — same envelope as R2..R5 (proven to fit):
  u16*   hcomb  = (u16*)(ws);
  u16*   xpbuf  = (u16*)(ws + 201129984L);
  u16*   gru    = (u16*)(ws + 335216640L);
  float* scores = (float*)(ws + 469303296L);
  u16*   wihb   = (u16*)(ws + 471398400L);
  u16*   w1b    = (u16*)(ws + 471545856L);
  float* hstate = (float*)(ws + 471562240L);

  k_prep<<<288, 256, 0, stream>>>(gwih, aw1, wihb, w1b);
  k_front<<<512, 256, 0, stream>>>(x, proj_w, proj_b, beta1, beta2, hcomb);
  for (int c = 0; c < 3; ++c) {
    long rowbase = (long)c * TCH * 512;
    k_xproj<<<dim3(1364, 3), 256, 0, stream>>>(hcomb + rowbase * NC, wihb, gbih, xpbuf);
    k_gru<<<512, 256, 0, stream>>>(xpbuf, gwhh, gbhh, gru + rowbase * NH, hstate, c == 0 ? 1 : 0);
  }
  k_score<<<4092, 256, 0, stream>>>(gru, w1b, ab1, aw2, ab2, scores);
  k_attn<<<512, 256, 0, stream>>>(scores, gru, hw, hb, out);
}

// Round 7
// 1123.233 us; speedup vs baseline: 1.1711x; 1.1711x over previous
//
#include <hip/hip_runtime.h>

typedef unsigned short u16;
typedef __attribute__((ext_vector_type(8))) short short8;
typedef __attribute__((ext_vector_type(4))) float f32x4;

__device__ __forceinline__ u16 f2bf(float f) {
  union { float f; unsigned u; } v; v.f = f;
  unsigned r = v.u + 0x7fffu + ((v.u >> 16) & 1u);
  return (u16)(r >> 16);
}
__device__ __forceinline__ u16 truncbf(float f) {
  union { float f; unsigned u; } v; v.f = f;
  return (u16)(v.u >> 16);
}
__device__ __forceinline__ float bf2f(u16 h) {
  union { unsigned u; float f; } v; v.u = ((unsigned)h) << 16;
  return v.f;
}
// async global->LDS, 16B per lane; LDS dest = wave-uniform base (HW adds lane*16), 16B aligned
__device__ __forceinline__ void gll16(const void* g, void* l) {
  __builtin_amdgcn_global_load_lds((const __attribute__((address_space(1))) unsigned*)g,
                                   (__attribute__((address_space(3))) unsigned*)l, 16, 0, 0);
}

// Problem constants
#define BATCH 512
#define TS 1023          // T-1
#define NF 64
#define NS 128
#define NH 128
#define NG 384           // 3H
#define NC 192           // F + SNN
#define TCH 341          // t-chunk for xproj/gru; M per chunk = 341*512 = 1364*128
// All big tensors are t-major: tensor[t][b][feat], flat row m = t*512 + b.

// ---------------- P: weight bf16 conversion ----------------
__global__ void k_prep(const float* __restrict__ wih, const float* __restrict__ w1,
                       u16* __restrict__ wihb, u16* __restrict__ w1b) {
  int i = blockIdx.x * 256 + threadIdx.x;
  if (i < NG * NC) wihb[i] = f2bf(wih[i]);
  if (i < 64 * NH) w1b[i] = f2bf(w1[i]);
}

// ---------------- FRONT: fused delta-GEMM (bf16 hi/lo MFMA) + SNN scan + raw ----------------
// One block per batch b (512 blocks, 256 threads). Streams t in 16 tiles of 64.
__global__ __launch_bounds__(256) void k_front(const float* __restrict__ x,
                                               const float* __restrict__ pw,
                                               const float* __restrict__ pb,
                                               const float* __restrict__ beta1,
                                               const float* __restrict__ beta2,
                                               u16* __restrict__ hcomb) {
  __shared__ alignas(16) float xs[17 * 256];        // 17,408 B: up to 65 rows x 64 f + pad
  __shared__ alignas(16) u16 Ahi[64 * 64], Alo[64 * 64];   // 8 KB each, XOR-swizzled rows
  __shared__ alignas(16) u16 Bhi[128 * 64], Blo[128 * 64]; // 16 KB each, XOR-swizzled rows
  __shared__ float hst[64 * 138];                   // 35,328 B (pad 138: quad-writes 2-way free)
  const int tid = threadIdx.x, lane = tid & 63, w = tid >> 6;
  const int m16 = lane & 15, quad = lane >> 4;
  const int b = blockIdx.x;
  const float* xb = x + (long)b * 65536;

  // P0: B = pw hi/lo split, row-major [n][64k], chunk-swizzled
  #pragma unroll
  for (int j = 0; j < 4; ++j) {
    int cid = tid * 4 + j;           // 0..1023
    int n = cid >> 3, ch = cid & 7;
    const float* src = pw + n * 64 + ch * 8;
    short8 h8, l8;
    #pragma unroll
    for (int jj = 0; jj < 8; ++jj) {
      float v = src[jj];
      u16 hh = truncbf(v);
      float l = v - bf2f(hh);
      h8[jj] = (short)hh; l8[jj] = (short)f2bf(l);
    }
    int chs = ch ^ (n & 7);
    *(short8*)(Bhi + n * 64 + chs * 8) = h8;
    *(short8*)(Blo + n * 64 + chs * 8) = l8;
  }
  float b1v = 0.f, b2v = 0.f, m1 = 0.f, s1 = 0.f, m2 = 0.f, s2 = 0.f;
  if (tid < 128) {
    b1v = fminf(fmaxf(beta1[tid], 0.f), 0.99f);
    b2v = fminf(fmaxf(beta2[tid], 0.f), 0.99f);
  }
  const int tm = (w >> 1) * 32, nn = (w & 1) * 64;
  float pbv[4];
  #pragma unroll
  for (int ni = 0; ni < 4; ++ni) pbv[ni] = pb[nn + ni * 16 + m16];

  for (int tile = 0; tile < 16; ++tile) {
    const int t0 = tile * 64;
    const int tl = (TS - t0 < 64) ? (TS - t0) : 64;       // 64, last tile 63
    const int rows = (1024 - t0 < 65) ? (1024 - t0) : 65; // 65, last tile 64
    const int bytes = rows * 256;
    // P1: stage x rows t0..t0+rows-1 (contiguous) via async global->LDS
    const int nch = (bytes + 1023) >> 10;
    for (int c = w; c < nch; c += 4) {
      int off = c * 1024 + lane * 16;
      if (off > bytes - 16) off = bytes - 16;
      gll16((const char*)xb + (long)t0 * 256 + off, (char*)xs + c * 1024);
    }
    __syncthreads();
    // P2: A = delta hi/lo (row r holds t = t0+r), swizzled
    {
      int r = tid >> 2, kq = tid & 3;
      const float* x0 = xs + r * 64 + kq * 16;
      short8 h8[2], l8[2];
      #pragma unroll
      for (int cc = 0; cc < 2; ++cc)
        #pragma unroll
        for (int jj = 0; jj < 8; ++jj) {
          float d = x0[64 + cc * 8 + jj] - x0[cc * 8 + jj];
          u16 hh = truncbf(d);
          float l = d - bf2f(hh);
          h8[cc][jj] = (short)hh; l8[cc][jj] = (short)f2bf(l);
        }
      #pragma unroll
      for (int cc = 0; cc < 2; ++cc) {
        int chs = (kq * 2 + cc) ^ (r & 7);
        *(short8*)(Ahi + r * 64 + chs * 8) = h8[cc];
        *(short8*)(Alo + r * 64 + chs * 8) = l8[cc];
      }
    }
    __syncthreads();
    // P3: MFMA 3-pass hi/lo, wave tile 32t x 64n
    f32x4 acc[2][4] = {};
    #pragma unroll
    for (int kc = 0; kc < 2; ++kc) {
      short8 ah[2], al[2], bh[4], bl[4];
      #pragma unroll
      for (int mi = 0; mi < 2; ++mi) {
        int row = tm + mi * 16 + m16;
        int chs = (kc * 4 + quad) ^ (row & 7);
        ah[mi] = *(const short8*)(Ahi + row * 64 + chs * 8);
        al[mi] = *(const short8*)(Alo + row * 64 + chs * 8);
      }
      #pragma unroll
      for (int ni = 0; ni < 4; ++ni) {
        int row = nn + ni * 16 + m16;
        int chs = (kc * 4 + quad) ^ (row & 7);
        bh[ni] = *(const short8*)(Bhi + row * 64 + chs * 8);
        bl[ni] = *(const short8*)(Blo + row * 64 + chs * 8);
      }
      #pragma unroll
      for (int mi = 0; mi < 2; ++mi)
        #pragma unroll
        for (int ni = 0; ni < 4; ++ni) {
          acc[mi][ni] = __builtin_amdgcn_mfma_f32_16x16x32_bf16(ah[mi], bh[ni], acc[mi][ni], 0, 0, 0);
          acc[mi][ni] = __builtin_amdgcn_mfma_f32_16x16x32_bf16(ah[mi], bl[ni], acc[mi][ni], 0, 0, 0);
          acc[mi][ni] = __builtin_amdgcn_mfma_f32_16x16x32_bf16(al[mi], bh[ni], acc[mi][ni], 0, 0, 0);
        }
    }
    // P4: hst[t][n] = acc + proj_b (C/D layout: col=lane&15, row=quad*4+reg)
    #pragma unroll
    for (int mi = 0; mi < 2; ++mi)
      #pragma unroll
      for (int ni = 0; ni < 4; ++ni)
        #pragma unroll
        for (int rr = 0; rr < 4; ++rr)
          hst[(tm + mi * 16 + quad * 4 + rr) * 138 + nn + ni * 16 + m16] = acc[mi][ni][rr] + pbv[ni];
    __syncthreads();
    // P5: SNN scan (threads 0..127) + raw emit (threads 128..255)
    if (tid < 128) {
      const int n = tid;
      u16* dst = hcomb + ((long)t0 * 512 + b) * NC + 64 + n;
      for (int tt = 0; tt < tl; tt += 8) {
        float v[8];
        #pragma unroll
        for (int jj = 0; jj < 8; ++jj) {
          int t = tt + jj; if (t > 63) t = 63;
          v[jj] = hst[t * 138 + n];
        }
        #pragma unroll
        for (int jj = 0; jj < 8; ++jj) {
          int t = tt + jj;
          if (t < tl) {
            m1 = b1v * m1 + v[jj] - s1;
            s1 = (m1 > 1.0f) ? 1.0f : 0.0f;
            m2 = b2v * m2 + s1 - s2;
            s2 = (m2 > 1.0f) ? 1.0f : 0.0f;
            dst[(long)t * (512 * NC)] = f2bf(m2);
          }
        }
      }
    } else {
      const int f = tid & 63, half = (tid >> 6) & 1;
      for (int r = half; r < tl; r += 2)
        hcomb[((long)(t0 + r) * 512 + b) * NC + f] = f2bf(xs[(r + 1) * 64 + f]);
    }
    __syncthreads();
  }
}

// ---------------- C: x_proj chunk = h_comb @ W_ih^T + b_ih (bf16 MFMA) ----------------
// grid (1364, 3), block 256. BM=128 BN=128 BK=32, 6 k-chunks. hc/xp are chunk-base pointers.
__global__ __launch_bounds__(256) void k_xproj(const u16* __restrict__ hc, const u16* __restrict__ wih,
                                               const float* __restrict__ bih, u16* __restrict__ xp) {
  __shared__ alignas(16) u16 As[4096], Bs[4096];   // 8KB each: 128 rows x 32 bf16 (64B rows)
  const int tid = threadIdx.x, lane = tid & 63, w = tid >> 6;
  const int m16 = lane & 15, quad = lane >> 4;
  const long row0 = (long)blockIdx.x * 128;
  const int n0 = blockIdx.y * 128;
  const int wm = (w >> 1) * 64, wn = (w & 1) * 64;
  f32x4 acc[4][4] = {};
  const char* gA = (const char*)hc + (row0 + (lane >> 2)) * (NC * 2) + (lane & 3) * 16;
  const char* gB = (const char*)wih + (long)(n0 + (lane >> 2)) * (NC * 2) + (lane & 3) * 16;
  for (int kc = 0; kc < 6; ++kc) {
    #pragma unroll
    for (int i = 0; i < 2; ++i) {
      int q = i * 4 + w;
      gll16(gA + (long)q * 16 * (NC * 2) + kc * 64, (char*)As + q * 1024);
      gll16(gB + (long)q * 16 * (NC * 2) + kc * 64, (char*)Bs + q * 1024);
    }
    __syncthreads();
    short8 af[4], bfr[4];
    #pragma unroll
    for (int mi = 0; mi < 4; ++mi) af[mi] = *(const short8*)((const char*)As + (wm + mi * 16 + m16) * 64 + quad * 16);
    #pragma unroll
    for (int ni = 0; ni < 4; ++ni) bfr[ni] = *(const short8*)((const char*)Bs + (wn + ni * 16 + m16) * 64 + quad * 16);
    #pragma unroll
    for (int mi = 0; mi < 4; ++mi)
      #pragma unroll
      for (int ni = 0; ni < 4; ++ni)
        acc[mi][ni] = __builtin_amdgcn_mfma_f32_16x16x32_bf16(af[mi], bfr[ni], acc[mi][ni], 0, 0, 0);
    __syncthreads();
  }
  #pragma unroll
  for (int ni = 0; ni < 4; ++ni) {
    int n = n0 + wn + ni * 16 + m16;
    float bias = bih[n];
    #pragma unroll
    for (int mi = 0; mi < 4; ++mi) {
      long r = row0 + wm + mi * 16 + quad * 4;
      #pragma unroll
      for (int rr = 0; rr < 4; ++rr)
        xp[(r + rr) * NG + n] = f2bf(acc[mi][ni][rr] + bias);
    }
  }
}

// ---------------- D: GRU scan — 2 batches/block, A-row replication {4b,4b+8}, no scratch ----------------
// 256 blocks x 256 threads. Batch b lives at A rows 4b and 4b+8 -> D row = quad*4+reg, reg 0 of
// quad q = gh[b=q&1]. Lane (w,quad,m16) owns (b=quad&1, j=32w+(quad>>1)*16+m16): all 64 lanes
// distinct -> zero redundancy, gates read MFMA acc regs directly (no LDS scratch, no cross-lane).
// K=128 split into two 2-deep MFMA chains (accA: k0-63, accB: k64-127) + scalar add.
// xp prefetched 8 steps ahead; gout buffered 8 steps -> 7 of 8 barriers drain nothing.
__global__ __launch_bounds__(256, 1) void k_gru(const u16* __restrict__ xp, const float* __restrict__ whh,
                                                const float* __restrict__ bhh, u16* __restrict__ gout,
                                                float* __restrict__ h_state, int first) {
  __shared__ alignas(16) u16 frag[2 * 2048];   // two 4KB A-fragment ping-pong buffers
  const int tid = threadIdx.x, lane = tid & 63, w = tid >> 6;
  const int m16 = lane & 15, quad = lane >> 4;
  const long bg0 = (long)blockIdx.x * 2;
  // zero both buffers (invalid A rows harmless for D rows we read, but keep deterministic)
  {
    short8 z8 = {};
    *(short8*)((char*)frag + tid * 16) = z8;
    *(short8*)((char*)frag + 4096 + tid * 16) = z8;
  }
  // W_hh fragments: tile nt = g*2+hh -> B rows g*128 + 32w + hh*16 + m16, k = c*32 + quad*8 + i
  short8 wf[6][4];
  #pragma unroll
  for (int g = 0; g < 3; ++g)
    #pragma unroll
    for (int hh = 0; hh < 2; ++hh)
      #pragma unroll
      for (int c = 0; c < 4; ++c) {
        const float* src = whh + (long)(g * 128 + 32 * w + hh * 16 + m16) * NH + c * 32 + quad * 8;
        short8 v;
        #pragma unroll
        for (int jj = 0; jj < 8; ++jj) v[jj] = (short)f2bf(src[jj]);
        wf[g * 2 + hh][c] = v;
      }
  const int bq = quad & 1, hq = quad >> 1;
  const int j = 32 * w + hq * 16 + m16;        // this lane's j (all 64 lanes distinct (bq,j))
  const long brow = bg0 + bq;
  const float br_ = bhh[j], bz_ = bhh[128 + j], bn_ = bhh[256 + j];
  float h = first ? 0.f : h_state[brow * NH + j];
  // frag byte addr for A[m=4*bq][k=j] (c = j>>5 = w): second copy at m+8 -> +128 bytes
  const int fragoff = w * 1024 + 64 * bq + 256 * (hq * 2 + (m16 >> 3)) + 2 * (m16 & 7);
  __syncthreads();                             // zero-init visible
  {
    u16 hb0 = f2bf(h);
    *(u16*)((char*)frag + fragoff) = hb0;
    *(u16*)((char*)frag + fragoff + 128) = hb0;
  }
  const u16* xbase = xp + brow * NG + j;       // + t*512*NG; gates at +0,+128,+256
  u16 pr[8], pz[8], pn[8], sbuf[8];
  #pragma unroll
  for (int u = 0; u < 8; ++u) {
    const u16* xr = xbase + (long)u * (512 * NG);
    pr[u] = xr[0]; pz[u] = xr[128]; pn[u] = xr[256];
  }
  __syncthreads();

#define GRU_STEP(T, U)                                                                     \
  {                                                                                        \
    const int cur = ((T) & 1) * 4096, nxt = 4096 - cur;                                    \
    short8 af[4];                                                                          \
    _Pragma("unroll")                                                                      \
    for (int c = 0; c < 4; ++c)                                                            \
      af[c] = *(const short8*)((const char*)frag + cur + c * 1024 + lane * 16);            \
    f32x4 zero = {0.f, 0.f, 0.f, 0.f};                                                     \
    f32x4 accA[6], accB[6];                                                                \
    _Pragma("unroll")                                                                      \
    for (int nt = 0; nt < 6; ++nt) {                                                       \
      accA[nt] = __builtin_amdgcn_mfma_f32_16x16x32_bf16(af[0], wf[nt][0], zero, 0, 0, 0); \
      accB[nt] = __builtin_amdgcn_mfma_f32_16x16x32_bf16(af[2], wf[nt][2], zero, 0, 0, 0); \
    }                                                                                      \
    _Pragma("unroll")                                                                      \
    for (int nt = 0; nt < 6; ++nt) {                                                       \
      accA[nt] = __builtin_amdgcn_mfma_f32_16x16x32_bf16(af[1], wf[nt][1], accA[nt], 0, 0, 0); \
      accB[nt] = __builtin_amdgcn_mfma_f32_16x16x32_bf16(af[3], wf[nt][3], accB[nt], 0, 0, 0); \
    }                                                                                      \
    float ghr = (hq ? (accA[1][0] + accB[1][0]) : (accA[0][0] + accB[0][0])) + br_;        \
    float ghz = (hq ? (accA[3][0] + accB[3][0]) : (accA[2][0] + accB[2][0])) + bz_;        \
    float ghn = (hq ? (accA[5][0] + accB[5][0]) : (accA[4][0] + accB[4][0])) + bn_;        \
    float xrv = bf2f(pr[U]), xzv = bf2f(pz[U]), xnv = bf2f(pn[U]);                         \
    float rg = 1.f / (1.f + __expf(-(xrv + ghr)));                                         \
    float zg = 1.f / (1.f + __expf(-(xzv + ghz)));                                         \
    float niv = xnv + rg * ghn;                                                            \
    float ng = 1.f - 2.f / (1.f + __expf(2.f * niv));                                      \
    h = (1.f - zg) * ng + zg * h;                                                          \
    u16 hb = f2bf(h);                                                                      \
    sbuf[U] = hb;                                                                          \
    *(u16*)((char*)frag + nxt + fragoff) = hb;                                             \
    *(u16*)((char*)frag + nxt + fragoff + 128) = hb;                                       \
    __syncthreads();                                                                       \
  }

  for (int t8 = 0; t8 < 336; t8 += 8) {
    // flush previous group's stores (none on first group)
    if (t8 > 0) {
      #pragma unroll
      for (int u = 0; u < 8; ++u)
        gout[((long)(t8 - 8 + u) * 512 + brow) * NH + j] = sbuf[u];
    }
    // prefetch next group's xp (t8+8 .. t8+15, clamped)
    u16 npr[8], npz[8], npn[8];
    #pragma unroll
    for (int u = 0; u < 8; ++u) {
      long tp = t8 + 8 + u; if (tp > TCH - 1) tp = TCH - 1;
      const u16* xr = xbase + tp * (512 * NG);
      npr[u] = xr[0]; npz[u] = xr[128]; npn[u] = xr[256];
    }
    GRU_STEP(t8 + 0, 0) GRU_STEP(t8 + 1, 1) GRU_STEP(t8 + 2, 2) GRU_STEP(t8 + 3, 3)
    GRU_STEP(t8 + 4, 4) GRU_STEP(t8 + 5, 5) GRU_STEP(t8 + 6, 6) GRU_STEP(t8 + 7, 7)
    #pragma unroll
    for (int u = 0; u < 8; ++u) { pr[u] = npr[u]; pz[u] = npz[u]; pn[u] = npn[u]; }
  }
  // flush group t=328..335
  #pragma unroll
  for (int u = 0; u < 8; ++u)
    gout[((long)(328 + u) * 512 + brow) * NH + j] = sbuf[u];
  // tail t = 336..340 (pre holds them), store immediately
  #pragma unroll
  for (int u = 0; u < 5; ++u) {
    GRU_STEP(336 + u, u)
    gout[((long)(336 + u) * 512 + brow) * NH + j] = sbuf[u];
  }
#undef GRU_STEP
  h_state[brow * NH + j] = h;
}

// ---------------- E: scores = relu(gru@W1^T + b1)@w2 + b2 (bf16 MFMA, fused 2nd layer) ----------------
// grid 4092, block 256. BM=128, BN=64, K=128 (4 chunks). M-rows = t*512+b (t-major).
__global__ __launch_bounds__(256) void k_score(const u16* __restrict__ gbf, const u16* __restrict__ w1,
                                               const float* __restrict__ b1, const float* __restrict__ w2,
                                               const float* __restrict__ b2, float* __restrict__ scores) {
  __shared__ alignas(16) u16 Gs[4096], Ws[2048];
  const int tid = threadIdx.x, lane = tid & 63, w = tid >> 6;
  const int m16 = lane & 15, quad = lane >> 4;
  const long row0 = (long)blockIdx.x * 128;
  f32x4 acc[2][4] = {};
  const char* gG = (const char*)gbf + (row0 + (lane >> 2)) * (NH * 2) + (lane & 3) * 16;
  const char* gW = (const char*)w1 + (long)(w * 16 + (lane >> 2)) * (NH * 2) + (lane & 3) * 16;
  for (int kc = 0; kc < 4; ++kc) {
    #pragma unroll
    for (int i = 0; i < 2; ++i) {
      int q = i * 4 + w;
      gll16(gG + (long)q * 16 * (NH * 2) + kc * 64, (char*)Gs + q * 1024);
    }
    gll16(gW + kc * 64, (char*)Ws + w * 1024);
    __syncthreads();
    short8 af[2], bfr[4];
    #pragma unroll
    for (int mi = 0; mi < 2; ++mi) af[mi] = *(const short8*)((const char*)Gs + (w * 32 + mi * 16 + m16) * 64 + quad * 16);
    #pragma unroll
    for (int ni = 0; ni < 4; ++ni) bfr[ni] = *(const short8*)((const char*)Ws + (ni * 16 + m16) * 64 + quad * 16);
    #pragma unroll
    for (int mi = 0; mi < 2; ++mi)
      #pragma unroll
      for (int ni = 0; ni < 4; ++ni)
        acc[mi][ni] = __builtin_amdgcn_mfma_f32_16x16x32_bf16(af[mi], bfr[ni], acc[mi][ni], 0, 0, 0);
    __syncthreads();
  }
  float b2v = b2[0];
  float w2v[4], b1v[4];
  #pragma unroll
  for (int ni = 0; ni < 4; ++ni) { w2v[ni] = w2[ni * 16 + m16]; b1v[ni] = b1[ni * 16 + m16]; }
  #pragma unroll
  for (int mi = 0; mi < 2; ++mi) {
    #pragma unroll
    for (int rr = 0; rr < 4; ++rr) {
      float v = 0.f;
      #pragma unroll
      for (int ni = 0; ni < 4; ++ni) {
        float hv = acc[mi][ni][rr] + b1v[ni];
        hv = hv > 0.f ? hv : 0.f;
        v = fmaf(hv, w2v[ni], v);
      }
      v += __shfl_xor(v, 1, 64); v += __shfl_xor(v, 2, 64);
      v += __shfl_xor(v, 4, 64); v += __shfl_xor(v, 8, 64);
      if (m16 == 0) scores[row0 + w * 32 + mi * 16 + quad * 4 + rr] = v + b2v;
    }
  }
}

// ---------------- F: softmax over t + weighted sum + head ----------------
// 512 blocks (one per batch) x 256 threads. scores/gout are t-major.
__global__ __launch_bounds__(256) void k_attn(const float* __restrict__ scores, const u16* __restrict__ gout,
                                              const float* __restrict__ headw, const float* __restrict__ headb,
                                              float* __restrict__ out) {
  __shared__ float sc[TS];
  __shared__ float red[8];
  __shared__ float part[8][132];
  __shared__ float hann[128];
  const int tid = threadIdx.x, lane = tid & 63, w = tid >> 6;
  const long b = blockIdx.x;
  const float* srow = scores + b;        // stride 512 per t
  float s0[4];
  #pragma unroll
  for (int i = 0; i < 4; ++i) {
    int t = tid + i * 256;
    s0[i] = (t < TS) ? srow[(long)t * 512] : -1e30f;
  }
  float mx = fmaxf(fmaxf(s0[0], s0[1]), fmaxf(s0[2], s0[3]));
  #pragma unroll
  for (int off = 32; off > 0; off >>= 1) mx = fmaxf(mx, __shfl_xor(mx, off, 64));
  if (lane == 0) red[w] = mx;
  __syncthreads();
  mx = fmaxf(fmaxf(red[0], red[1]), fmaxf(red[2], red[3]));
  float sum = 0.f;
  #pragma unroll
  for (int i = 0; i < 4; ++i) {
    int t = tid + i * 256;
    if (t < TS) { float e = __expf(s0[i] - mx); sc[t] = e; sum += e; }
  }
  #pragma unroll
  for (int off = 32; off > 0; off >>= 1) sum += __shfl_xor(sum, off, 64);
  if (lane == 0) red[4 + w] = sum;
  __syncthreads();
  float inv = 1.f / (red[4] + red[5] + red[6] + red[7]);
  const int jg = tid & 31, sl = tid >> 5;
  float acc[4] = {0.f, 0.f, 0.f, 0.f};
  const u16* gbase = gout + b * NH + jg * 4;   // stride 512*NH per t
  for (int t = sl; t < TS; t += 8) {
    float wt = sc[t];
    ushort4 g4 = *(const ushort4*)(gbase + (long)t * (512 * NH));
    acc[0] = fmaf(wt, bf2f(g4.x), acc[0]);
    acc[1] = fmaf(wt, bf2f(g4.y), acc[1]);
    acc[2] = fmaf(wt, bf2f(g4.z), acc[2]);
    acc[3] = fmaf(wt, bf2f(g4.w), acc[3]);
  }
  #pragma unroll
  for (int i = 0; i < 4; ++i) part[sl][jg * 4 + i] = acc[i];
  __syncthreads();
  if (tid < 128) {
    float v = 0.f;
    #pragma unroll
    for (int s = 0; s < 8; ++s) v += part[s][tid];
    hann[tid] = v * inv;
  }
  __syncthreads();
  if (tid < 24) {
    float a = headb[tid];
    const float* hwr = headw + tid * 128;
    for (int k = 0; k < 128; k += 4) {
      float4 h4 = *(const float4*)&hann[k];
      float4 w4 = *(const float4*)&hwr[k];
      a = fmaf(h4.x, w4.x, a); a = fmaf(h4.y, w4.y, a);
      a = fmaf(h4.z, w4.z, a); a = fmaf(h4.w, w4.w, a);
    }
    out[b * 24 + tid] = a;
  }
}

extern "C" void kernel_launch(void* const* d_in, const int* in_sizes, int n_in,
                              void* d_out, int out_size, void* d_ws, size_t ws_size,
                              hipStream_t stream) {
  const float* x      = (const float*)d_in[0];
  const float* proj_w = (const float*)d_in[1];
  const float* proj_b = (const float*)d_in[2];
  const float* beta1  = (const float*)d_in[3];
  const float* beta2  = (const float*)d_in[4];
  const float* gwih   = (const float*)d_in[5];
  const float* gwhh   = (const float*)d_in[6];
  const float* gbih   = (const float*)d_in[7];
  const float* gbhh   = (const float*)d_in[8];
  const float* aw1    = (const float*)d_in[9];
  const float* ab1    = (const float*)d_in[10];
  const float* aw2    = (const float*)d_in[11];
  const float* ab2    = (const float*)d_in[12];
  const float* hw     = (const float*)d_in[13];
  const float* hb     = (const float*)d_in[14];
  float* out = (float*)d_out;
  char* ws = (char*)d_ws;

  // Workspace (bytes) — same envelope as R2..R6 (proven to fit):
  u16*   hcomb  = (u16*)(ws);
  u16*   xpbuf  = (u16*)(ws + 201129984L);
  u16*   gru    = (u16*)(ws + 335216640L);
  float* scores = (float*)(ws + 469303296L);
  u16*   wihb   = (u16*)(ws + 471398400L);
  u16*   w1b    = (u16*)(ws + 471545856L);
  float* hstate = (float*)(ws + 471562240L);

  k_prep<<<288, 256, 0, stream>>>(gwih, aw1, wihb, w1b);
  k_front<<<512, 256, 0, stream>>>(x, proj_w, proj_b, beta1, beta2, hcomb);
  for (int c = 0; c < 3; ++c) {
    long rowbase = (long)c * TCH * 512;
    k_xproj<<<dim3(1364, 3), 256, 0, stream>>>(hcomb + rowbase * NC, wihb, gbih, xpbuf);
    k_gru<<<256, 256, 0, stream>>>(xpbuf, gwhh, gbhh, gru + rowbase * NH, hstate, c == 0 ? 1 : 0);
  }
  k_score<<<4092, 256, 0, stream>>>(gru, w1b, ab1, aw2, ab2, scores);
  k_attn<<<512, 256, 0, stream>>>(scores, gru, hw, hb, out);
}